// Round 3
// baseline (66.927 us; speedup 1.0000x reference)
//
#include <hip/hip_runtime.h>

// HONU order-2, L=64: out[i] = b + sum_{j<=k} W[woff(j)+k-j] * x[i,j] * x[i,k]
// woff(j) = 64j - j(j-1)/2
//
// R4: latency-test restructure (T-B). One wave per row, no LDS, no barriers.
//   out[i] = b + sum_k x_k * z_k,   z_k = sum_{j<=k} W[woff(j)+k-j] * x_j
// Lane k owns x[i,k] (one coalesced 256B load per wave). Per literal j:
//   - W[cj + lane], cj = 63j - j(j-1)/2: contiguous row -> coalesced wave
//     load; W is 8.6 KB -> L1-resident after first use.
//   - mask (lane >= j): v_cmp + v_cndmask (lanes k<j contribute 0).
//   - x_j broadcast: v_readlane -> SGPR operand of the FMA.
// 16384 waves = 64 waves/CU (vs 16 before), ~24 VGPR, ~2.5 KB code,
// zero sync points: if the old 1-block/CU barrier structure was
// latency-bound, this collapses it; if dur_us is unchanged, the floor is
// the harness fill (40.5us) + launch overhead and we are done.

#define WAVES_PER_BLOCK 8
#define BLOCK (WAVES_PER_BLOCK * 64)

__global__ __launch_bounds__(BLOCK) void honu_kernel(
    const float* __restrict__ X, const float* __restrict__ W,
    const float* __restrict__ Bias, float* __restrict__ out, int nrows) {
  const int lane = threadIdx.x & 63;
  const int wave = threadIdx.x >> 6;
  const int row = blockIdx.x * WAVES_PER_BLOCK + wave;
  if (row >= nrows) return;

  // Coalesced: lane k reads x[row, k].
  const float xv = X[(size_t)row * 64 + lane];

  float z = 0.0f;
#pragma unroll
  for (int j = 0; j < 64; ++j) {
    const int cj = 63 * j - (j * (j - 1)) / 2;  // woff(j) - j, compile-time
    // Always in-bounds: cj + lane <= 2016 + 63 = 2079 < 2145.
    float w = W[cj + lane];
    w = (lane >= j) ? w : 0.0f;  // triangular mask, per-lane cndmask
    // Broadcast x_j to all lanes as an SGPR (all lanes active here).
    const float xj = __int_as_float(
        __builtin_amdgcn_readlane(__float_as_int(xv), j));
    z = __builtin_fmaf(w, xj, z);
  }

  // out[row] = bias + sum_k x_k * z_k : 6-step butterfly over 64 lanes.
  float p = xv * z;
#pragma unroll
  for (int off = 32; off > 0; off >>= 1) p += __shfl_xor(p, off);

  if (lane == 0) out[row] = p + Bias[0];
}

extern "C" void kernel_launch(void* const* d_in, const int* in_sizes, int n_in,
                              void* d_out, int out_size, void* d_ws,
                              size_t ws_size, hipStream_t stream) {
  const float* X = (const float*)d_in[0];     // (16384, 64) fp32
  const float* W = (const float*)d_in[1];     // (2145,) fp32 (first 2080 used)
  const float* Bias = (const float*)d_in[2];  // (1,) fp32
  float* out = (float*)d_out;                 // (16384,) fp32

  const int nrows = out_size;  // 16384
  const int grid = (nrows + WAVES_PER_BLOCK - 1) / WAVES_PER_BLOCK;
  honu_kernel<<<grid, BLOCK, 0, stream>>>(X, W, Bias, out, nrows);
}

// Round 4
// 61.658 us; speedup vs baseline: 1.0855x; 1.0855x over previous
//
#include <hip/hip_runtime.h>

// HONU order-2, L=64: out[i] = b + sum_{j<=k} W[woff(j)+k-j] * x[i,j] * x[i,k]
// woff(j) = 64j - j(j-1)/2  (lex order of combinations_with_replacement)
//
// R5: R0's structure (best measured: lane=row, scalar W via compile-time j,
// balanced triangular pairing) with 8 fat waves instead of 16.
// Evidence: R0(60.2) < R3(63.0, 2x FMA) < R4(66.9, vector W loads) -> kernel
// share scales with issued pipe work; R0's dominant cost is the DS pipe
// (784 ds_read_b32/block at ~5.8 cyc >> 1072 VALU cyc/SIMD). Halving the
// wave count halves LDS reads (wave S reads only x[4S..63] -> 400/block)
// while keeping total FMAs identical: wave S owns j in {4S..4S+3} u
// {60-4S..63-4S} = exactly 268 FMA/lane, all W indices compile-time ->
// uniform scalar loads. Occupancy drops 4->2 waves/SIMD, which R4 showed
// is not the limiter here.

#define ROWS 64
#define XSTRIDE 65  // +1 pad: bank = (65*lane+k)%32 = (lane+k)%32 -> 2-way, free
#define NWAVES 8
#define BLOCK (NWAVES * 64)

template <int J0, int J1>
__device__ __forceinline__ void accum_range(const float* __restrict__ W,
                                            const float (&x)[64],
                                            float& acc) {
#pragma unroll
  for (int j = J0; j < J1; ++j) {
    const int base = j * 64 - (j * (j - 1)) / 2;  // woff(j), compile-time
    float y = 0.0f;
#pragma unroll
    for (int k = j; k < 64; ++k) {
      y = __builtin_fmaf(W[base + (k - j)], x[k], y);
    }
    acc = __builtin_fmaf(x[j], y, acc);
  }
}

template <int S>
__device__ __forceinline__ float wave_work(const float* __restrict__ W,
                                           const float* __restrict__ xrow) {
  // Wave S needs only x[4S..63] (its smallest j is 4S; the high range
  // {60-4S..63-4S} is a subset for all S in 0..7).
  float x[64];
#pragma unroll
  for (int k = 4 * S; k < 64; ++k) x[k] = xrow[k];
  float acc = 0.0f;
  accum_range<4 * S, 4 * S + 4>(W, x, acc);
  accum_range<60 - 4 * S, 64 - 4 * S>(W, x, acc);
  return acc;
}

__global__ __launch_bounds__(BLOCK, 2) void honu_kernel(
    const float* __restrict__ X, const float* __restrict__ W,
    const float* __restrict__ Bias, float* __restrict__ out, int nrows) {
  __shared__ float tile[ROWS * XSTRIDE];  // 16.6 KB
  __shared__ float part[NWAVES][64];      // 2 KB

  const int tid = threadIdx.x;
  const int lane = tid & 63;
  const int wave = tid >> 6;
  const int row0 = blockIdx.x * ROWS;

  // Coalesced staging: thread tid loads float4 #(2*tid) and #(2*tid+1) of
  // the 64x64 tile (512 threads x 32 B = whole tile, fully contiguous).
  {
    const int r = tid >> 3;        // row within tile
    const int c = (tid & 7) << 3;  // starting col (8 floats per thread)
    float4 a = make_float4(0.f, 0.f, 0.f, 0.f);
    float4 b = a;
    if (row0 + r < nrows) {
      const float4* src = reinterpret_cast<const float4*>(X) +
                          ((size_t)(row0 + r) * 16 + ((tid & 7) << 1));
      a = src[0];
      b = src[1];
    }
    float* dst = &tile[r * XSTRIDE + c];
    dst[0] = a.x; dst[1] = a.y; dst[2] = a.z; dst[3] = a.w;
    dst[4] = b.x; dst[5] = b.y; dst[6] = b.z; dst[7] = b.w;
  }
  __syncthreads();

  const float* xrow = &tile[lane * XSTRIDE];
  float acc = 0.0f;
  switch (wave) {  // wave-uniform branch
    case 0:  acc = wave_work<0>(W, xrow); break;
    case 1:  acc = wave_work<1>(W, xrow); break;
    case 2:  acc = wave_work<2>(W, xrow); break;
    case 3:  acc = wave_work<3>(W, xrow); break;
    case 4:  acc = wave_work<4>(W, xrow); break;
    case 5:  acc = wave_work<5>(W, xrow); break;
    case 6:  acc = wave_work<6>(W, xrow); break;
    default: acc = wave_work<7>(W, xrow); break;
  }
  part[wave][lane] = acc;
  __syncthreads();

  if (tid < 64) {
    const int orow = row0 + tid;
    if (orow < nrows) {
      float r = Bias[0];
#pragma unroll
      for (int w = 0; w < NWAVES; ++w) r += part[w][tid];
      out[orow] = r;
    }
  }
}

extern "C" void kernel_launch(void* const* d_in, const int* in_sizes, int n_in,
                              void* d_out, int out_size, void* d_ws,
                              size_t ws_size, hipStream_t stream) {
  const float* X = (const float*)d_in[0];     // (16384, 64) fp32
  const float* W = (const float*)d_in[1];     // (2145,) fp32 (first 2080 used)
  const float* Bias = (const float*)d_in[2];  // (1,) fp32
  float* out = (float*)d_out;                 // (16384,) fp32

  const int nrows = out_size;  // 16384
  const int grid = (nrows + ROWS - 1) / ROWS;
  honu_kernel<<<grid, BLOCK, 0, stream>>>(X, W, Bias, out, nrows);
}

// Round 5
// 60.243 us; speedup vs baseline: 1.1109x; 1.0235x over previous
//
#include <hip/hip_runtime.h>

// HONU order-2, L=64: out[i] = b + sum_{j<=k} W[woff(j)+k-j] * x[i,j] * x[i,k]
// woff(j) = 64j - j(j-1)/2  (lex order of combinations_with_replacement)
//
// R6 = R0 restored (best measured: 60.2 us). Session ablation record:
//   R0 16-wave templates          60.2  <- this source
//   R3 unified masked loop        63.0  (I-fetch theory refuted)
//   R4 wave-per-row no-LDS        66.9  (latency/occupancy theory refuted)
//   R5 8 fat waves, half DS reads 61.7  (DS-pipe theory refuted)
// Timed region decomposes as ~40.5us harness fill (256 MiB @ 83% HBM peak,
// at the achievable ceiling) + ~17us fixed reset/launch overhead + ~3us
// kernel share already at its critical-path floor. Confirmation run; if
// dur_us = 60.2 +- 1.5, declare roofline.
//
// Layout: 256 blocks x 1024 threads (16 waves = 4 waves/SIMD). Block owns
// 64 rows (lane = row). X-tile staged via LDS: coalesced float4 loads,
// LDS row stride 65 keeps accesses <=2 lanes/bank (free on CDNA4). The 16
// waves split the triangular j-range with a compile-time balanced pairing
// (wave s: j in {2s,2s+1} U {62-2s,63-2s} -> exactly 134 FMAs each), so all
// W indices are compile-time constants -> uniform scalar loads.

#define ROWS 64
#define XSTRIDE 65  // +1 pad: LDS bank = (65*lane + k)%32 = (lane+k)%32 -> 2-way, free

template <int J0, int J1>
__device__ __forceinline__ void accum_range(const float* __restrict__ W,
                                            const float (&x)[64],
                                            float& acc) {
#pragma unroll
  for (int j = J0; j < J1; ++j) {
    const int base = j * 64 - (j * (j - 1)) / 2;  // woff(j), compile-time
    float y = 0.0f;
#pragma unroll
    for (int k = j; k < 64; ++k) {
      y = __builtin_fmaf(W[base + (k - j)], x[k], y);
    }
    acc = __builtin_fmaf(x[j], y, acc);
  }
}

template <int S>
__device__ __forceinline__ float wave_work(const float* __restrict__ W,
                                           const float* __restrict__ xrow) {
  // Wave S needs only x[2S..63] (its smallest j is 2S).
  float x[64];
#pragma unroll
  for (int k = 2 * S; k < 64; ++k) x[k] = xrow[k];
  float acc = 0.0f;
  accum_range<2 * S, 2 * S + 2>(W, x, acc);
  accum_range<62 - 2 * S, 64 - 2 * S>(W, x, acc);
  return acc;
}

__global__ __launch_bounds__(1024, 4) void honu_kernel(
    const float* __restrict__ X, const float* __restrict__ W,
    const float* __restrict__ Bias, float* __restrict__ out, int nrows) {
  __shared__ float tile[ROWS * XSTRIDE];  // 16.6 KB
  __shared__ float part[16][64];          // 4 KB

  const int tid = threadIdx.x;
  const int lane = tid & 63;
  const int wave = tid >> 6;
  const int row0 = blockIdx.x * ROWS;

  // Coalesced staging: thread tid loads float4 #tid of the 64x64 tile.
  {
    const int r = tid >> 4;         // row within tile
    const int c = (tid & 15) << 2;  // starting col
    float4 v = make_float4(0.f, 0.f, 0.f, 0.f);
    if (row0 + r < nrows) {
      v = reinterpret_cast<const float4*>(X)[(size_t)(row0 + r) * 16 +
                                             (tid & 15)];
    }
    float* dst = &tile[r * XSTRIDE + c];
    dst[0] = v.x;
    dst[1] = v.y;
    dst[2] = v.z;
    dst[3] = v.w;
  }
  __syncthreads();

  const float* xrow = &tile[lane * XSTRIDE];
  float acc = 0.0f;
  switch (wave) {  // wave-uniform branch
    case 0:  acc = wave_work<0>(W, xrow);  break;
    case 1:  acc = wave_work<1>(W, xrow);  break;
    case 2:  acc = wave_work<2>(W, xrow);  break;
    case 3:  acc = wave_work<3>(W, xrow);  break;
    case 4:  acc = wave_work<4>(W, xrow);  break;
    case 5:  acc = wave_work<5>(W, xrow);  break;
    case 6:  acc = wave_work<6>(W, xrow);  break;
    case 7:  acc = wave_work<7>(W, xrow);  break;
    case 8:  acc = wave_work<8>(W, xrow);  break;
    case 9:  acc = wave_work<9>(W, xrow);  break;
    case 10: acc = wave_work<10>(W, xrow); break;
    case 11: acc = wave_work<11>(W, xrow); break;
    case 12: acc = wave_work<12>(W, xrow); break;
    case 13: acc = wave_work<13>(W, xrow); break;
    case 14: acc = wave_work<14>(W, xrow); break;
    default: acc = wave_work<15>(W, xrow); break;
  }
  part[wave][lane] = acc;
  __syncthreads();

  if (tid < 64) {
    const int orow = row0 + tid;
    if (orow < nrows) {
      float r = Bias[0];
#pragma unroll
      for (int w = 0; w < 16; ++w) r += part[w][tid];
      out[orow] = r;
    }
  }
}

extern "C" void kernel_launch(void* const* d_in, const int* in_sizes, int n_in,
                              void* d_out, int out_size, void* d_ws,
                              size_t ws_size, hipStream_t stream) {
  const float* X = (const float*)d_in[0];     // (16384, 64) fp32
  const float* W = (const float*)d_in[1];     // (2145,) fp32 (first 2080 used)
  const float* Bias = (const float*)d_in[2];  // (1,) fp32
  float* out = (float*)d_out;                 // (16384,) fp32

  const int nrows = out_size;  // 16384
  const int grid = (nrows + ROWS - 1) / ROWS;
  honu_kernel<<<grid, 1024, 0, stream>>>(X, W, Bias, out, nrows);
}